// Round 6
// baseline (482.878 us; speedup 1.0000x reference)
//
#include <hip/hip_runtime.h>

// ---------------------------------------------------------------------------
// DepTreeLSTM on MI355X — round 6: split emb-GEMM out of the recurrence.
//   K0a: leaf fused GEMM (K=256, N=384) + LSTM epilogue (no children).
//   K0b: internal nodes pre[g][512] = emb @ [W_iou | W_f]  (bf16, raw).
//   lvl d=1..5: A=[ht0|ht1] (K=256) x BU (640 cols) + pre-add epilogue.
// h mirrored as bf16 (hbuf) to halve gather traffic. c stays f32.
// B streamed per-ks via global_load_lds DMA, double-buffered (R5 scheme).
// A staged in row-image LDS [rows][264] (coalesced loads, 2-way-max banks).
// ws: BW 0 | BU 256K | cbuf f32 @1MB | hbuf bf16 @+132MB | pre bf16 @+198MB.
// ---------------------------------------------------------------------------

typedef float f32x4 __attribute__((ext_vector_type(4)));
typedef __bf16 bf16x8 __attribute__((ext_vector_type(8)));
typedef unsigned short u16x8 __attribute__((ext_vector_type(8)));

__device__ __forceinline__ unsigned short f2bf(float x) {
  unsigned int u = __float_as_uint(x);
  return (unsigned short)((u + 0x7fffu + ((u >> 16) & 1u)) >> 16);
}
__device__ __forceinline__ float bf2f(unsigned short u) {
  return __uint_as_float(((unsigned int)u) << 16);
}
__device__ __forceinline__ float sigf(float x) { return 1.f / (1.f + __expf(-x)); }
__device__ __forceinline__ float tanhfast(float x) {
  return 1.f - 2.f / (__expf(2.f * x) + 1.f);
}
__device__ __forceinline__ void gld_lds16(const unsigned short* g, unsigned short* l) {
  __builtin_amdgcn_global_load_lds((const __attribute__((address_space(1))) void*)g,
                                   (__attribute__((address_space(3))) void*)l, 16, 0, 0);
}

#define ASTR 264  // A row-image stride in shorts (K=256 + 8 pad)

// Fragment pack: X[((T*8+ks)*64+lane)*8+j], lane=kq*16+cl, col=T*16+cl,
// k=ks*32+kq*8+j (K=256 for both).
// BW (32 tiles): col<384: W_iou[k][col]; else W_f[k][col-384].
// BU (40 tiles): col<384: U_iou[k][col]; else U_f_w[k][col-384] (f0|f1).
__global__ void prep_kernel(const float* __restrict__ Wi, const float* __restrict__ Ui,
                            const float* __restrict__ Wf, const float* __restrict__ Uf,
                            unsigned short* __restrict__ BW, unsigned short* __restrict__ BU) {
  int idx = blockIdx.x * 512 + threadIdx.x;  // 0 .. 294911
  if (idx < 131072) {
    int j = idx & 7, lane = (idx >> 3) & 63, ks = (idx >> 9) & 7, T = idx >> 12;
    int cl = lane & 15, kq = lane >> 4;
    int c = T * 16 + cl, k = ks * 32 + kq * 8 + j;
    BW[idx] = f2bf((c < 384) ? Wi[k * 384 + c] : Wf[k * 128 + (c - 384)]);
  } else {
    int i2 = idx - 131072;
    int j = i2 & 7, lane = (i2 >> 3) & 63, ks = (i2 >> 9) & 7, T = i2 >> 12;
    int cl = lane & 15, kq = lane >> 4;
    int c = T * 16 + cl, k = ks * 32 + kq * 8 + j;
    BU[i2] = f2bf((c < 384) ? Ui[k * 384 + c] : Uf[k * 256 + (c - 384)]);
  }
}

// ---- K0a: leaf fused GEMM. 512 thr, 64 rows, NT=3 (i,o,u). ----
__global__ __launch_bounds__(512, 2) void leaf_kernel(
    const float* __restrict__ emb, const unsigned short* __restrict__ BW,
    const float* __restrict__ b_iou,
    float* __restrict__ hout, float* __restrict__ cbuf,
    unsigned short* __restrict__ hbuf) {
  constexpr int NT = 3;
  __shared__ unsigned short Ar[64 * ASTR];
  __shared__ unsigned short Bb[2][NT * 8 * 512];

  const int tid = threadIdx.x;
  const int lane = tid & 63;
  const int w = tid >> 6;
  const int m0 = blockIdx.x * 64;

  // DMA B slice ks=0 (overlaps A staging)
#pragma unroll
  for (int c = 0; c < NT; ++c) {
    const int T = c * 8 + w;
    gld_lds16(&BW[(size_t)(T * 8 + 0) * 512 + lane * 8], &Bb[0][T * 512]);
  }
  // stage emb rows (coalesced 1KB/row)
#pragma unroll
  for (int it = 0; it < 8; ++it) {
    const int f = it * 512 + tid;
    const int r = f >> 6, c4 = f & 63;
    const int m = m0 + r;
    const int g = (m >> 5) * 63 + (m & 31);
    const float4 v = *(const float4*)&emb[(size_t)g * 256 + c4 * 4];
    ushort4 p;
    p.x = f2bf(v.x); p.y = f2bf(v.y); p.z = f2bf(v.z); p.w = f2bf(v.w);
    *(ushort4*)&Ar[r * ASTR + c4 * 4] = p;
  }
  __syncthreads();

  f32x4 acc[4][NT];
#pragma unroll
  for (int mt = 0; mt < 4; ++mt)
#pragma unroll
    for (int t = 0; t < NT; ++t) acc[mt][t] = (f32x4){0.f, 0.f, 0.f, 0.f};

  const int cl = lane & 15, kq = lane >> 4;
  int cur = 0;
  for (int ks = 0; ks < 8; ++ks) {
    if (ks + 1 < 8) {
#pragma unroll
      for (int c = 0; c < NT; ++c) {
        const int T = c * 8 + w;
        gld_lds16(&BW[(size_t)(T * 8 + ks + 1) * 512 + lane * 8], &Bb[cur ^ 1][T * 512]);
      }
    }
    bf16x8 b[NT];
#pragma unroll
    for (int t = 0; t < NT; ++t)
      b[t] = *(const bf16x8*)&Bb[cur][(t * 8 + w) * 512 + lane * 8];
#pragma unroll
    for (int mt = 0; mt < 4; ++mt) {
      const bf16x8 a = *(const bf16x8*)&Ar[(mt * 16 + cl) * ASTR + ks * 32 + kq * 8];
#pragma unroll
      for (int t = 0; t < NT; ++t)
        acc[mt][t] = __builtin_amdgcn_mfma_f32_16x16x32_bf16(a, b[t], acc[mt][t], 0, 0, 0);
    }
    __syncthreads();
    cur ^= 1;
  }

  const int rb = (lane >> 4) << 2;
  const int hcol = w * 16 + cl;
  const float bi = b_iou[hcol], bo = b_iou[128 + hcol], bu = b_iou[256 + hcol];
#pragma unroll
  for (int mt = 0; mt < 4; ++mt) {
#pragma unroll
    for (int r = 0; r < 4; ++r) {
      const int m = m0 + (mt << 4) + rb + r;
      const int g = (m >> 5) * 63 + (m & 31);
      const float cn = sigf(acc[mt][0][r] + bi) * tanhfast(acc[mt][2][r] + bu);
      const float hn = sigf(acc[mt][1][r] + bo) * tanhfast(cn);
      cbuf[(size_t)g * 128 + hcol] = cn;
      hout[(size_t)g * 128 + hcol] = hn;
      hbuf[(size_t)g * 128 + hcol] = f2bf(hn);
    }
  }
}

// ---- K0b: internal-node pre GEMM. 512 thr, 64 rows, NT=4 (i,o,u,Xf). ----
__global__ __launch_bounds__(512, 2) void pre_kernel(
    const float* __restrict__ emb, const unsigned short* __restrict__ BW,
    unsigned short* __restrict__ pre) {
  constexpr int NT = 4;
  __shared__ unsigned short Ar[64 * ASTR];
  __shared__ unsigned short Bb[2][NT * 8 * 512];

  const int tid = threadIdx.x;
  const int lane = tid & 63;
  const int w = tid >> 6;
  const int m0 = blockIdx.x * 64;

#pragma unroll
  for (int c = 0; c < NT; ++c) {
    const int T = c * 8 + w;
    gld_lds16(&BW[(size_t)(T * 8 + 0) * 512 + lane * 8], &Bb[0][T * 512]);
  }
#pragma unroll
  for (int it = 0; it < 8; ++it) {
    const int f = it * 512 + tid;
    const int r = f >> 6, c4 = f & 63;
    const unsigned m = m0 + r;
    const unsigned tree = m / 31u;
    const int g = tree * 63 + 32 + (m - tree * 31u);
    const float4 v = *(const float4*)&emb[(size_t)g * 256 + c4 * 4];
    ushort4 p;
    p.x = f2bf(v.x); p.y = f2bf(v.y); p.z = f2bf(v.z); p.w = f2bf(v.w);
    *(ushort4*)&Ar[r * ASTR + c4 * 4] = p;
  }
  __syncthreads();

  f32x4 acc[4][NT];
#pragma unroll
  for (int mt = 0; mt < 4; ++mt)
#pragma unroll
    for (int t = 0; t < NT; ++t) acc[mt][t] = (f32x4){0.f, 0.f, 0.f, 0.f};

  const int cl = lane & 15, kq = lane >> 4;
  int cur = 0;
  for (int ks = 0; ks < 8; ++ks) {
    if (ks + 1 < 8) {
#pragma unroll
      for (int c = 0; c < NT; ++c) {
        const int T = c * 8 + w;
        gld_lds16(&BW[(size_t)(T * 8 + ks + 1) * 512 + lane * 8], &Bb[cur ^ 1][T * 512]);
      }
    }
    bf16x8 b[NT];
#pragma unroll
    for (int t = 0; t < NT; ++t)
      b[t] = *(const bf16x8*)&Bb[cur][(t * 8 + w) * 512 + lane * 8];
#pragma unroll
    for (int mt = 0; mt < 4; ++mt) {
      const bf16x8 a = *(const bf16x8*)&Ar[(mt * 16 + cl) * ASTR + ks * 32 + kq * 8];
#pragma unroll
      for (int t = 0; t < NT; ++t)
        acc[mt][t] = __builtin_amdgcn_mfma_f32_16x16x32_bf16(a, b[t], acc[mt][t], 0, 0, 0);
    }
    __syncthreads();
    cur ^= 1;
  }

  const int rb = (lane >> 4) << 2;
  const int hcol = w * 16 + cl;
#pragma unroll
  for (int mt = 0; mt < 4; ++mt) {
#pragma unroll
    for (int r = 0; r < 4; ++r) {
      const unsigned m = m0 + (mt << 4) + rb + r;
      const unsigned tree = m / 31u;
      const int g = tree * 63 + 32 + (m - tree * 31u);
#pragma unroll
      for (int t = 0; t < NT; ++t)
        pre[(size_t)g * 512 + t * 128 + hcol] = f2bf(acc[mt][t][r]);
    }
  }
}

// ---- levels 1..5: A=[ht0|ht1] K=256, BU 40 tiles, NT=5, pre-add epilogue ----
__global__ __launch_bounds__(512, 2) void lvl_kernel(
    const float* __restrict__ cmask,
    const int* __restrict__ cidx, const int* __restrict__ ctype,
    const unsigned short* __restrict__ BU,
    const float* __restrict__ b_iou, const float* __restrict__ ufb,
    const float* __restrict__ bf_,
    const unsigned short* __restrict__ pre,
    float* __restrict__ hout, float* __restrict__ cbuf,
    unsigned short* __restrict__ hbuf,
    int lc, int cntm1, int offs) {
  constexpr int NT = 5;
  __shared__ unsigned short Ar[64 * ASTR];
  __shared__ unsigned short Bb[2][NT * 8 * 512];

  const int tid = threadIdx.x;
  const int lane = tid & 63;
  const int w = tid >> 6;
  const int m0 = blockIdx.x * 64;

#pragma unroll
  for (int c = 0; c < NT; ++c) {
    const int T = c * 8 + w;
    gld_lds16(&BU[(size_t)(T * 8 + 0) * 512 + lane * 8], &Bb[0][T * 512]);
  }

  // stage A: wave q handles 32-col chunk q (q<4: ht0, q>=4: ht1), 64 rows
  {
    const int rblk = tid & 63;
    const int q = tid >> 6;
    const int m = m0 + rblk;
    const int g = ((m >> lc) * 63) + offs + (m & cntm1);
    const int ch0 = cidx[2 * g], ch1 = cidx[2 * g + 1];
    const int ty0 = ctype[2 * g], ty1 = ctype[2 * g + 1];
    const float c0 = cmask[2 * g], c1 = cmask[2 * g + 1];
    const int sel = q >> 2;  // 0: type-0 row, 1: type-1 row
    const float wA = (ty0 == sel) ? c0 : 0.f;
    const float wB = (ty1 == sel) ? c1 : 0.f;
    const int hc = (q & 3) * 32;
#pragma unroll
    for (int s = 0; s < 4; ++s) {
      const u16x8 va = *(const u16x8*)&hbuf[(size_t)ch0 * 128 + hc + 8 * s];
      const u16x8 vb = *(const u16x8*)&hbuf[(size_t)ch1 * 128 + hc + 8 * s];
      u16x8 o;
#pragma unroll
      for (int e = 0; e < 8; ++e)
        o[e] = f2bf(wA * bf2f(va[e]) + wB * bf2f(vb[e]));
      *(u16x8*)&Ar[rblk * ASTR + q * 32 + 8 * s] = o;
    }
  }
  __syncthreads();

  f32x4 acc[4][NT];
#pragma unroll
  for (int mt = 0; mt < 4; ++mt)
#pragma unroll
    for (int t = 0; t < NT; ++t) acc[mt][t] = (f32x4){0.f, 0.f, 0.f, 0.f};

  const int cl = lane & 15, kq = lane >> 4;
  int cur = 0;
  for (int ks = 0; ks < 8; ++ks) {
    if (ks + 1 < 8) {
#pragma unroll
      for (int c = 0; c < NT; ++c) {
        const int T = c * 8 + w;
        gld_lds16(&BU[(size_t)(T * 8 + ks + 1) * 512 + lane * 8], &Bb[cur ^ 1][T * 512]);
      }
    }
    bf16x8 b[NT];
#pragma unroll
    for (int t = 0; t < NT; ++t)
      b[t] = *(const bf16x8*)&Bb[cur][(t * 8 + w) * 512 + lane * 8];
#pragma unroll
    for (int mt = 0; mt < 4; ++mt) {
      const bf16x8 a = *(const bf16x8*)&Ar[(mt * 16 + cl) * ASTR + ks * 32 + kq * 8];
#pragma unroll
      for (int t = 0; t < NT; ++t)
        acc[mt][t] = __builtin_amdgcn_mfma_f32_16x16x32_bf16(a, b[t], acc[mt][t], 0, 0, 0);
    }
    __syncthreads();
    cur ^= 1;
  }

  const int rb = (lane >> 4) << 2;
  const int hcol = w * 16 + cl;
  const float bi = b_iou[hcol], bo = b_iou[128 + hcol], bu = b_iou[256 + hcol];
  const float f0b = ufb[hcol], f1b = ufb[128 + hcol], bfv = bf_[hcol];
#pragma unroll
  for (int mt = 0; mt < 4; ++mt) {
#pragma unroll
    for (int r = 0; r < 4; ++r) {
      const int m = m0 + (mt << 4) + rb + r;
      const int g = ((m >> lc) * 63) + offs + (m & cntm1);
      const int ch0 = cidx[2 * g], ch1 = cidx[2 * g + 1];
      const int ty0 = ctype[2 * g], ty1 = ctype[2 * g + 1];
      const float c0v = cmask[2 * g], c1v = cmask[2 * g + 1];
      const unsigned short* pg = &pre[(size_t)g * 512 + hcol];
      const float iv = acc[mt][0][r] + bf2f(pg[0]) + bi;
      const float ov = acc[mt][1][r] + bf2f(pg[128]) + bo;
      const float uv = acc[mt][2][r] + bf2f(pg[256]) + bu;
      const float Xf = bf2f(pg[384]);
      const float f0 = acc[mt][3][r] + f0b;
      const float f1 = acc[mt][4][r] + f1b;
      const float fa = (ty0 == 0) ? f0 : f1;
      const float fb = (ty1 == 0) ? f0 : f1;
      const float ft0 = sigf(Xf + fa + bfv);
      const float ft1 = sigf(Xf + fb + bfv);
      const float ccell = ft0 * cbuf[(size_t)ch0 * 128 + hcol] * c0v +
                          ft1 * cbuf[(size_t)ch1 * 128 + hcol] * c1v;
      const float cn = sigf(iv) * tanhfast(uv) + ccell;
      const float hn = sigf(ov) * tanhfast(cn);
      cbuf[(size_t)g * 128 + hcol] = cn;
      hout[(size_t)g * 128 + hcol] = hn;
      hbuf[(size_t)g * 128 + hcol] = f2bf(hn);
    }
  }
}

extern "C" void kernel_launch(void* const* d_in, const int* in_sizes, int n_in,
                              void* d_out, int out_size, void* d_ws, size_t ws_size,
                              hipStream_t stream) {
  (void)in_sizes; (void)n_in; (void)out_size; (void)ws_size;
  const float* emb   = (const float*)d_in[0];
  const float* cmask = (const float*)d_in[1];
  const float* W_iou = (const float*)d_in[2];
  const float* U_iou = (const float*)d_in[3];
  const float* b_iou = (const float*)d_in[4];
  const float* W_f   = (const float*)d_in[5];
  const float* U_f_w = (const float*)d_in[6];
  const float* U_f_b = (const float*)d_in[7];
  const float* b_f   = (const float*)d_in[8];
  const int* cidx    = (const int*)d_in[9];
  const int* ctype   = (const int*)d_in[10];
  float* hout = (float*)d_out;

  char* ws = (char*)d_ws;
  unsigned short* BW   = (unsigned short*)ws;                          // 262144 B
  unsigned short* BU   = (unsigned short*)(ws + 262144);               // 327680 B
  float* cbuf          = (float*)(ws + (1u << 20));                    // 132120576 B
  unsigned short* hbuf = (unsigned short*)(ws + 133169152ull);         // 66060288 B
  unsigned short* pre  = (unsigned short*)(ws + 199229440ull);         // 264241152 B

  prep_kernel<<<576, 512, 0, stream>>>(W_iou, U_iou, W_f, U_f_w, BW, BU);

  pre_kernel<<<1984, 512, 0, stream>>>(emb, BW, pre);           // 126976 internal rows
  leaf_kernel<<<2048, 512, 0, stream>>>(emb, BW, b_iou, hout, cbuf, hbuf);  // 131072 rows

  lvl_kernel<<<1024, 512, 0, stream>>>(cmask, cidx, ctype, BU, b_iou, U_f_b, b_f,
                                       pre, hout, cbuf, hbuf, 4, 15, 32);
  lvl_kernel<<<512, 512, 0, stream>>>(cmask, cidx, ctype, BU, b_iou, U_f_b, b_f,
                                      pre, hout, cbuf, hbuf, 3, 7, 48);
  lvl_kernel<<<256, 512, 0, stream>>>(cmask, cidx, ctype, BU, b_iou, U_f_b, b_f,
                                      pre, hout, cbuf, hbuf, 2, 3, 56);
  lvl_kernel<<<128, 512, 0, stream>>>(cmask, cidx, ctype, BU, b_iou, U_f_b, b_f,
                                      pre, hout, cbuf, hbuf, 1, 1, 60);
  lvl_kernel<<<64, 512, 0, stream>>>(cmask, cidx, ctype, BU, b_iou, U_f_b, b_f,
                                     pre, hout, cbuf, hbuf, 0, 0, 62);
}